// Round 8
// baseline (89.480 us; speedup 1.0000x reference)
//
#include <hip/hip_runtime.h>
#include <math.h>

#define BB 64
#define D0 768
#define D2 2304
#define HH 512
#define BBHH (BB*HH)
#define NG0 8192
#define NC0 8
#define NCH1 11
#define TK1 32
#define TK2 64
#define NC1 (TK1*NC0)   /* 256 */
#define NC2 (TK2*NCH1)  /* 704 */
#define SPA 2
#define SPB 2
#define SPC 6
#define NSL (SPA+SPB+SPC)   /* 10 */

__device__ __forceinline__ float sigmoidf_(float x){ return 1.0f/(1.0f+expf(-x)); }
__device__ __forceinline__ float geluf_(float x){ return 0.5f*x*(1.0f+erff(x*0.70710678118654752f)); }
__device__ __forceinline__ unsigned long long maxu64_(unsigned long long a, unsigned long long b){ return a>b?a:b; }
__device__ __forceinline__ float dot8_(float4 ha, float4 hb, float4 a, float4 c){
  return ha.x*a.x+ha.y*a.y+ha.z*a.z+ha.w*a.w + hb.x*c.x+hb.y*c.y+hb.z*c.z+hb.w*c.w;
}

// Block-wide bitonic sort of 256 u64 keys, DESCENDING. One key per thread.
__device__ __forceinline__ unsigned long long bitonic256_desc(
    unsigned long long key, int tid, unsigned long long* sbuf)
{
  #pragma unroll
  for (int k = 2; k <= 256; k <<= 1) {
    #pragma unroll
    for (int j = k >> 1; j > 0; j >>= 1) {
      unsigned long long other;
      if (j >= 64) {
        __syncthreads();
        sbuf[tid] = key;
        __syncthreads();
        other = sbuf[tid ^ j];
      } else {
        other = __shfl_xor(key, j, 64);
      }
      bool keep_max = ((tid & j) == 0) == ((tid & k) == 0);
      key = keep_max ? (key > other ? key : other)
                     : (key < other ? key : other);
    }
  }
  return key;
}

// ===== K1: partial GEMMs (160 blocks) + E0 L3-prefetch (96 blocks) ==========
__global__ __launch_bounds__(256) void gemm_h_kernel(
    const float* __restrict__ feat5, const float* __restrict__ feat8,
    const float* __restrict__ featcat,
    const float* __restrict__ W0, const float* __restrict__ W1,
    const float* __restrict__ W2, const float* __restrict__ E0,
    float* __restrict__ P, float* __restrict__ dummy)
{
  __shared__ __align__(16) float At[32][68];
  __shared__ __align__(16) float Bt[32][36];
  const int bid = blockIdx.x, tid = threadIdx.x;
  if (bid >= 160) {
    // stream E0 through the cache hierarchy so K2's reads hit L3.
    // 96 blocks x 256 threads, grid-stride over 1M float4.
    const float4* e4 = (const float4*)E0;
    const int total = NG0*HH/4;                 // 1048576
    float acc = 0.f;
    for (int i = (bid-160)*256 + tid; i < total; i += 96*256) {
      float4 v = e4[i];
      acc += v.x + v.y + v.z + v.w;
    }
    if (acc == 1.0e38f) dummy[bid] = acc;       // never true; defeats DCE
    return;
  }
  const float* X; const float* W; int Dm, split, jt, slice;
  if (bid < 32)      { X=feat5;   W=W0; Dm=D0; int l=bid;    split=l&1; jt=(l>>1)*32; slice=split; }
  else if (bid < 64) { X=feat8;   W=W1; Dm=D0; int l=bid-32; split=l&1; jt=(l>>1)*32; slice=SPA+split; }
  else               { X=featcat; W=W2; Dm=D2; int l=bid-64; split=l%6; jt=(l/6)*32;  slice=SPA+SPB+split; }
  float* Pb = P + (size_t)slice*BBHH;
  int k0 = split*384;
  int ti = tid >> 4, tj = tid & 15;
  float acc[4][2] = {};
  for (int ks = 0; ks < 384; ks += 32) {
    #pragma unroll
    for (int it = 0; it < 2; ++it) {
      int q = tid + it*256;
      int b = q & 63, kq = q >> 6;
      float4 v = *(const float4*)(X + (size_t)b*Dm + k0 + ks + kq*4);
      At[kq*4+0][b]=v.x; At[kq*4+1][b]=v.y; At[kq*4+2][b]=v.z; At[kq*4+3][b]=v.w;
    }
    {
      int j4 = tid & 7, kk = tid >> 3;
      float4 v = *(const float4*)(W + (size_t)(k0+ks+kk)*HH + jt + j4*4);
      *(float4*)&Bt[kk][j4*4] = v;
    }
    __syncthreads();
    #pragma unroll
    for (int k = 0; k < 32; ++k) {
      float4 a = *(const float4*)&At[k][ti*4];
      float2 b = *(const float2*)&Bt[k][tj*2];
      float av[4] = {a.x,a.y,a.z,a.w};
      float bv[2] = {b.x,b.y};
      #pragma unroll
      for (int r=0;r<4;++r)
        #pragma unroll
        for (int c=0;c<2;++c) acc[r][c] += av[r]*bv[c];
    }
    __syncthreads();
  }
  #pragma unroll
  for (int r=0;r<4;++r)
    #pragma unroll
    for (int c=0;c<2;++c)
      Pb[(size_t)(ti*4+r)*HH + jt + tj*2 + c] = acc[r][c];
}

// ===== K2: level0, 512 blocks (2/CU), XCD-localized E0 tiles ================
__global__ __launch_bounds__(256,2) void level0_kernel(
    const float* __restrict__ P, const float* __restrict__ b0v,
    const float* __restrict__ E0, float* __restrict__ p0out)
{
  __shared__ __align__(16) float At[32][20];
  __shared__ __align__(16) float Bt[32][68];
  const int bid = blockIdx.x, tid = threadIdx.x;
  const int slot = bid >> 3;
  const int gt = (bid & 7) * 16 + (slot >> 2);
  const int btile = slot & 3;
  const int ti = tid >> 4, tj = tid & 15;
  float acc[4] = {};
  for (int ks = 0; ks < HH; ks += 32) {
    {
      int bb = tid & 15, kq = tid >> 4;
      float2 a = make_float2(0.f, 0.f);
      #pragma unroll
      for (int s=0;s<SPA;++s){
        float2 p = *(const float2*)(P + (size_t)s*BBHH
                        + (size_t)(btile*16+bb)*HH + ks + kq*2);
        a.x += p.x; a.y += p.y;
      }
      float2 bv = *(const float2*)(b0v + ks + kq*2);
      At[kq*2+0][bb] = geluf_(a.x + bv.x);
      At[kq*2+1][bb] = geluf_(a.y + bv.y);
    }
    #pragma unroll
    for (int it=0; it<2; ++it) {
      int q = tid + it*256; int g = q & 63, kq = q >> 6;
      float4 v = *(const float4*)(E0 + (size_t)(gt*64+g)*HH + ks + kq*4);
      Bt[kq*4+0][g]=v.x; Bt[kq*4+1][g]=v.y; Bt[kq*4+2][g]=v.z; Bt[kq*4+3][g]=v.w;
    }
    __syncthreads();
    #pragma unroll
    for (int k=0;k<32;++k) {
      float a = At[k][ti];
      float4 b = *(const float4*)&Bt[k][tj*4];
      acc[0] += a*b.x; acc[1] += a*b.y; acc[2] += a*b.z; acc[3] += a*b.w;
    }
    __syncthreads();
  }
  #pragma unroll
  for (int c=0;c<4;++c)
    p0out[(size_t)(btile*16 + ti)*NG0 + gt*64 + tj*4 + c] = sigmoidf_(acc[c]);
}

// ===== K3: redundant topk1 (x8) + h1-in-LDS + pipelined level1 gather =======
// 512 blocks (2/CU): b = bid&63, q = bid>>6 (0..7); ytiles {q, q+8}
__global__ __launch_bounds__(256,2) void topk1_level1_kernel(
    const float* __restrict__ p0, const int* __restrict__ g0,
    const float* __restrict__ P, const float* __restrict__ b1v,
    const float* __restrict__ E1,
    int* __restrict__ cands1_i, float* __restrict__ o_c1,
    float* __restrict__ o_p1, float* __restrict__ o_w1)
{
  const int bid = blockIdx.x, tid = threadIdx.x;
  const int b = bid & 63, q = bid >> 6;
  const int lane = tid & 63, wid = tid >> 6;
  __shared__ float h1row[HH];
  __shared__ unsigned long long sbuf[256];
  __shared__ unsigned long long slist[256];
  __shared__ float s_sc[TK1];
  __shared__ int   s_idx[TK1];
  __shared__ int   scnt;
  {
    int j = tid*2;
    float ax=0.f, ay=0.f;
    #pragma unroll
    for (int s=0;s<SPB;++s){
      float2 v = *(const float2*)(P + (size_t)(SPA+s)*BBHH + (size_t)b*HH + j);
      ax += v.x; ay += v.y;
    }
    float2 bv = *(const float2*)(b1v + j);
    h1row[j]   = geluf_(ax + bv.x);
    h1row[j+1] = geluf_(ay + bv.y);
  }
  if (tid==0) scnt = 0;
  const float* row = p0 + (size_t)b*NG0;
  const float4* rp = (const float4*)(row + tid*32);
  unsigned long long m = 0ull;
  #pragma unroll
  for (int t=0;t<8;++t){
    float4 v = rp[t];
    unsigned i0 = (unsigned)(tid*32 + t*4);
    m = maxu64_(m, ((unsigned long long)__float_as_uint(v.x)<<32) | (unsigned long long)(0xFFFFFFFFu-(i0+0)));
    m = maxu64_(m, ((unsigned long long)__float_as_uint(v.y)<<32) | (unsigned long long)(0xFFFFFFFFu-(i0+1)));
    m = maxu64_(m, ((unsigned long long)__float_as_uint(v.z)<<32) | (unsigned long long)(0xFFFFFFFFu-(i0+2)));
    m = maxu64_(m, ((unsigned long long)__float_as_uint(v.w)<<32) | (unsigned long long)(0xFFFFFFFFu-(i0+3)));
  }
  __syncthreads();
  unsigned long long sk = bitonic256_desc(m, tid, sbuf);
  __syncthreads();
  sbuf[tid] = sk;
  __syncthreads();
  unsigned long long t32 = sbuf[31];
  __syncthreads();
  #pragma unroll
  for (int t=0;t<8;++t){
    float4 v = rp[t];
    unsigned i0 = (unsigned)(tid*32 + t*4);
    unsigned long long k0 = ((unsigned long long)__float_as_uint(v.x)<<32) | (unsigned long long)(0xFFFFFFFFu-(i0+0));
    unsigned long long k1 = ((unsigned long long)__float_as_uint(v.y)<<32) | (unsigned long long)(0xFFFFFFFFu-(i0+1));
    unsigned long long k2 = ((unsigned long long)__float_as_uint(v.z)<<32) | (unsigned long long)(0xFFFFFFFFu-(i0+2));
    unsigned long long k3 = ((unsigned long long)__float_as_uint(v.w)<<32) | (unsigned long long)(0xFFFFFFFFu-(i0+3));
    if (k0 >= t32) { int p = atomicAdd(&scnt,1); if (p<256) slist[p]=k0; }
    if (k1 >= t32) { int p = atomicAdd(&scnt,1); if (p<256) slist[p]=k1; }
    if (k2 >= t32) { int p = atomicAdd(&scnt,1); if (p<256) slist[p]=k2; }
    if (k3 >= t32) { int p = atomicAdd(&scnt,1); if (p<256) slist[p]=k3; }
  }
  __syncthreads();
  int cnt = scnt;
  unsigned long long key2 = (tid < cnt) ? slist[tid] : 0ull;
  key2 = bitonic256_desc(key2, tid, sbuf);
  __syncthreads();
  sbuf[tid] = key2;
  __syncthreads();
  if (tid < TK1) {
    unsigned long long w = sbuf[tid];
    s_idx[tid] = (int)(0xFFFFFFFFu - (unsigned)(w & 0xFFFFFFFFull));
    s_sc[tid]  = __uint_as_float((unsigned)(w>>32));
  }
  __syncthreads();
  if (q==0 && tid < NC1) {
    int k = tid >> 3, c = tid & 7;
    int cand = g0[(size_t)s_idx[k]*NC0 + c];
    cands1_i[(size_t)b*NC1+tid] = cand;
    o_c1[(size_t)b*NC1+tid] = (float)cand;
  }
  float4 ha = *(const float4*)&h1row[lane*8];
  float4 hb = *(const float4*)&h1row[lane*8+4];
  // hoist the 8 candidate ids for this block's 2 ytiles
  int cid[2][4];
  #pragma unroll
  for (int j=0;j<2;++j){
    int cbase = (q + 8*j)*16 + wid*4;
    #pragma unroll
    for (int u=0;u<4;++u)
      cid[j][u] = g0[(size_t)s_idx[(cbase+u)>>3]*NC0 + ((cbase+u)&7)];
  }
  float4 a0,c0,a1,c1,a2,c2,a3,c3;
  {
    const float4* p0e=(const float4*)(E1+(size_t)cid[0][0]*HH);
    const float4* p1e=(const float4*)(E1+(size_t)cid[0][1]*HH);
    const float4* p2e=(const float4*)(E1+(size_t)cid[0][2]*HH);
    const float4* p3e=(const float4*)(E1+(size_t)cid[0][3]*HH);
    a0=p0e[lane*2]; c0=p0e[lane*2+1]; a1=p1e[lane*2]; c1=p1e[lane*2+1];
    a2=p2e[lane*2]; c2=p2e[lane*2+1]; a3=p3e[lane*2]; c3=p3e[lane*2+1];
  }
  #pragma unroll
  for (int j=0;j<2;++j){
    float4 na0,nc0,na1,nc1,na2,nc2,na3,nc3;
    if (j<1){
      const float4* p0e=(const float4*)(E1+(size_t)cid[1][0]*HH);
      const float4* p1e=(const float4*)(E1+(size_t)cid[1][1]*HH);
      const float4* p2e=(const float4*)(E1+(size_t)cid[1][2]*HH);
      const float4* p3e=(const float4*)(E1+(size_t)cid[1][3]*HH);
      na0=p0e[lane*2]; nc0=p0e[lane*2+1]; na1=p1e[lane*2]; nc1=p1e[lane*2+1];
      na2=p2e[lane*2]; nc2=p2e[lane*2+1]; na3=p3e[lane*2]; nc3=p3e[lane*2+1];
    }
    int cbase = (q + 8*j)*16 + wid*4;
    float s0=dot8_(ha,hb,a0,c0), s1=dot8_(ha,hb,a1,c1);
    float s2=dot8_(ha,hb,a2,c2), s3=dot8_(ha,hb,a3,c3);
    #pragma unroll
    for (int off=1; off<64; off<<=1) {
      s0 += __shfl_xor(s0, off);
      s1 += __shfl_xor(s1, off);
      s2 += __shfl_xor(s2, off);
      s3 += __shfl_xor(s3, off);
    }
    if (lane==0) {
      float p;
      p = sigmoidf_(s0); o_p1[(size_t)b*NC1+cbase+0]=p; o_w1[(size_t)b*NC1+cbase+0]=p*s_sc[(cbase+0)>>3];
      p = sigmoidf_(s1); o_p1[(size_t)b*NC1+cbase+1]=p; o_w1[(size_t)b*NC1+cbase+1]=p*s_sc[(cbase+1)>>3];
      p = sigmoidf_(s2); o_p1[(size_t)b*NC1+cbase+2]=p; o_w1[(size_t)b*NC1+cbase+2]=p*s_sc[(cbase+2)>>3];
      p = sigmoidf_(s3); o_p1[(size_t)b*NC1+cbase+3]=p; o_w1[(size_t)b*NC1+cbase+3]=p*s_sc[(cbase+3)>>3];
    }
    if (j<1){ a0=na0;c0=nc0;a1=na1;c1=nc1;a2=na2;c2=nc2;a3=na3;c3=nc3; }
  }
}

// ===== K4: redundant topk2 (x16) + h2-in-LDS + pipelined level2 gather ======
// 1024 blocks (4/CU): b = bid&63, q = bid>>6 (0..15); 44 cands/block,
// 11 iters x 4 waves x 1 cand, depth-2 pipeline.
__global__ __launch_bounds__(256,4) void topk2_level2_kernel(
    const float* __restrict__ p1, const int* __restrict__ cands1_i,
    const int* __restrict__ g1,
    const float* __restrict__ P, const float* __restrict__ b2v,
    const float* __restrict__ E2,
    float* __restrict__ o_c2, float* __restrict__ o_p2, float* __restrict__ o_w2)
{
  const int bid = blockIdx.x, tid = threadIdx.x;
  const int b = bid & 63, q = bid >> 6;     // q 0..15
  const int lane = tid & 63, wid = tid >> 6;
  __shared__ float h2row[HH];
  __shared__ unsigned long long sbuf[256];
  __shared__ float s_sc[TK2];
  __shared__ int   s_idx[TK2];
  __shared__ int   c1row[NC1];
  {
    int j = tid*2;
    float ax=0.f, ay=0.f;
    #pragma unroll
    for (int s=0;s<SPC;++s){
      float2 v = *(const float2*)(P + (size_t)(SPA+SPB+s)*BBHH + (size_t)b*HH + j);
      ax += v.x; ay += v.y;
    }
    float2 bv = *(const float2*)(b2v + j);
    h2row[j]   = geluf_(ax + bv.x);
    h2row[j+1] = geluf_(ay + bv.y);
  }
  c1row[tid] = cands1_i[(size_t)b*NC1 + tid];
  float v = p1[(size_t)b*NC1 + tid];
  unsigned long long key = ((unsigned long long)__float_as_uint(v)<<32) |
                           (unsigned long long)(0xFFFFFFFFu - (unsigned)tid);
  __syncthreads();
  key = bitonic256_desc(key, tid, sbuf);
  __syncthreads();
  sbuf[tid] = key;
  __syncthreads();
  if (tid < TK2) {
    unsigned long long w = sbuf[tid];
    s_idx[tid] = (int)(0xFFFFFFFFu - (unsigned)(w & 0xFFFFFFFFull));
    s_sc[tid]  = __uint_as_float((unsigned)(w>>32));
  }
  __syncthreads();
  if (q==0) {
    for (int e=tid; e<NC2; e+=256) {
      int k = e/NCH1, c = e - k*NCH1;
      int meta = c1row[s_idx[k]];
      int cand = g1[(size_t)meta*NCH1 + c];
      o_c2[(size_t)b*NC2+e] = (float)cand;
    }
  }
  float4 ha = *(const float4*)&h2row[lane*8];
  float4 hb = *(const float4*)&h2row[lane*8+4];
  int cid[11];
  #pragma unroll
  for (int j=0;j<11;++j){
    int cb = q*44 + j*4 + wid;
    int ki = cb/NCH1, ci = cb - ki*NCH1;
    cid[j] = g1[(size_t)c1row[s_idx[ki]]*NCH1 + ci];
  }
  float4 a0,c0;
  {
    const float4* pe=(const float4*)(E2+(size_t)cid[0]*HH);
    a0=pe[lane*2]; c0=pe[lane*2+1];
  }
  #pragma unroll
  for (int j=0;j<11;++j){
    float4 na0,nc0;
    if (j<10){
      const float4* pe=(const float4*)(E2+(size_t)cid[j+1]*HH);
      na0=pe[lane*2]; nc0=pe[lane*2+1];
    }
    int cb = q*44 + j*4 + wid;
    int ki = cb/NCH1;
    float s0 = dot8_(ha,hb,a0,c0);
    #pragma unroll
    for (int off=1; off<64; off<<=1) s0 += __shfl_xor(s0, off);
    if (lane==0) {
      float p = (s0==0.0f)?0.0f:sigmoidf_(s0);
      o_p2[(size_t)b*NC2+cb]=p; o_w2[(size_t)b*NC2+cb]=p*s_sc[ki];
    }
    if (j<10){ a0=na0;c0=nc0; }
  }
}

extern "C" void kernel_launch(void* const* d_in, const int* in_sizes, int n_in,
                              void* d_out, int out_size, void* d_ws, size_t ws_size,
                              hipStream_t stream) {
  const float* feat5   = (const float*)d_in[0];
  const float* feat8   = (const float*)d_in[1];
  const float* featcat = (const float*)d_in[2];
  const float* W0 = (const float*)d_in[3];
  const float* b0 = (const float*)d_in[4];
  const float* W1 = (const float*)d_in[5];
  const float* b1 = (const float*)d_in[6];
  const float* W2 = (const float*)d_in[7];
  const float* b2 = (const float*)d_in[8];
  const float* E0 = (const float*)d_in[9];
  const float* E1 = (const float*)d_in[10];
  const float* E2 = (const float*)d_in[11];
  const int*   g0 = (const int*)d_in[12];
  const int*   g1 = (const int*)d_in[13];

  float* out = (float*)d_out;
  float* ws  = (float*)d_ws;

  size_t off = 0;
  float* P = ws + off; off += (size_t)NSL*BBHH;
  int*   cands1_i = (int*)(ws + off); off += (size_t)BB*NC1;
  float* dummy = ws + off; off += 256;

  float* o_p0 = out;
  float* o_p1 = o_p0 + (size_t)BB*NG0;
  float* o_p2 = o_p1 + (size_t)BB*NC1;
  float* o_w1 = o_p2 + (size_t)BB*NC2;
  float* o_w2 = o_w1 + (size_t)BB*NC1;
  float* o_c1 = o_w2 + (size_t)BB*NC2;
  float* o_c2 = o_c1 + (size_t)BB*NC1;

  gemm_h_kernel<<<dim3(256), dim3(256), 0, stream>>>(feat5, feat8, featcat, W0, W1, W2, E0, P, dummy);
  level0_kernel<<<dim3(512), dim3(256), 0, stream>>>(P, b0, E0, o_p0);
  topk1_level1_kernel<<<dim3(512), dim3(256), 0, stream>>>(o_p0, g0, P, b1, E1,
      cands1_i, o_c1, o_p1, o_w1);
  topk2_level2_kernel<<<dim3(1024), dim3(256), 0, stream>>>(o_p1, cands1_i, g1, P, b2, E2,
      o_c2, o_p2, o_w2);
}